// Round 6
// baseline (237.042 us; speedup 1.0000x reference)
//
#include <hip/hip_runtime.h>
#include <hip/hip_bf16.h>

#define DIM 768
#define NH 12
#define HD 64
#define B_ 8
#define N_ 1024
#define BH (B_*NH)
#define EPS 1e-5f
// fold 1/sqrt(64) * log2(e) into q at pack time -> scores arrive in exp2 domain
#define QSCALE 0.18033688011112042f

typedef short s16x8 __attribute__((ext_vector_type(8)));
typedef float f32x4 __attribute__((ext_vector_type(4)));

__device__ __forceinline__ unsigned pk2bf(float a, float b) {
    __hip_bfloat162 h = __float22bfloat162_rn(float2{a, b});
    union { __hip_bfloat162 h; unsigned u; } cv; cv.h = h;
    return cv.u;
}

__device__ __forceinline__ float fexp2(float x) {
#if __has_builtin(__builtin_amdgcn_exp2f)
    return __builtin_amdgcn_exp2f(x);
#else
    return exp2f(x);
#endif
}

__device__ __forceinline__ void async_cp16(const void* g, void* l) {
    __builtin_amdgcn_global_load_lds(
        (const __attribute__((address_space(1))) unsigned*)g,
        (__attribute__((address_space(3))) unsigned*)l, 16, 0, 0);
}

// ---------------- Kernel 1: LayerNorm q,k + pack into fragment-native layouts ---------
__global__ __launch_bounds__(256)
void ln_pack_kernel(const float* __restrict__ QKV,
                    const float* __restrict__ qw, const float* __restrict__ qb,
                    const float* __restrict__ kw, const float* __restrict__ kb,
                    unsigned short* __restrict__ Qp,
                    unsigned short* __restrict__ Kp,
                    unsigned short* __restrict__ Vp) {
    int bid = blockIdx.x;
    int bh = bid >> 4, nt = bid & 15;
    int b = bh / NH, h = bh % NH;
    int tid = threadIdx.x, w = tid >> 6, ln = tid & 63;
    int rl = w * 16 + (ln >> 2);     // local row 0..63
    int part = ln & 3;               // dims part*16 .. part*16+15
    int n = nt * 64 + rl;

    __shared__ __attribute__((aligned(16))) unsigned short vlds[64][72];

    size_t base = ((size_t)(b * N_ + n)) * (3 * DIM) + h * HD + part * 16;
    float4 q[4], k[4], v[4];
    #pragma unroll
    for (int i = 0; i < 4; i++) {
        q[i] = *(const float4*)(QKV + base + i * 4);
        k[i] = *(const float4*)(QKV + base + DIM + i * 4);
        v[i] = *(const float4*)(QKV + base + 2 * DIM + i * 4);
    }

    float s1 = 0.f, s2 = 0.f, t1 = 0.f, t2 = 0.f;
    #pragma unroll
    for (int i = 0; i < 4; i++) {
        s1 += (q[i].x + q[i].y) + (q[i].z + q[i].w);
        s2 += (q[i].x * q[i].x + q[i].y * q[i].y) + (q[i].z * q[i].z + q[i].w * q[i].w);
        t1 += (k[i].x + k[i].y) + (k[i].z + k[i].w);
        t2 += (k[i].x * k[i].x + k[i].y * k[i].y) + (k[i].z * k[i].z + k[i].w * k[i].w);
    }
    #pragma unroll
    for (int m = 1; m < 4; m <<= 1) {
        s1 += __shfl_xor(s1, m, 64);
        s2 += __shfl_xor(s2, m, 64);
        t1 += __shfl_xor(t1, m, 64);
        t2 += __shfl_xor(t2, m, 64);
    }

    int ch = part >> 1;
    size_t tile = (((size_t)bh * 64 + (n >> 4)) * 2 + ch) * 512 + (size_t)(n & 15) * 32 + (part & 1) * 16;

    {   // q
        float mu = s1 * (1.0f / 64.0f);
        float var = s2 * (1.0f / 64.0f) - mu * mu;
        float rstd = rsqrtf(var + EPS);
        s16x8 c0, c1;
        #pragma unroll
        for (int i = 0; i < 4; i++) {
            const float4 wv = *(const float4*)(qw + part * 16 + i * 4);
            const float4 bv = *(const float4*)(qb + part * 16 + i * 4);
            float a0 = ((q[i].x - mu) * rstd * wv.x + bv.x) * QSCALE;
            float a1 = ((q[i].y - mu) * rstd * wv.y + bv.y) * QSCALE;
            float a2 = ((q[i].z - mu) * rstd * wv.z + bv.z) * QSCALE;
            float a3 = ((q[i].w - mu) * rstd * wv.w + bv.w) * QSCALE;
            unsigned u0 = pk2bf(a0, a1), u1 = pk2bf(a2, a3);
            if (i < 2) { ((unsigned*)&c0)[i * 2] = u0; ((unsigned*)&c0)[i * 2 + 1] = u1; }
            else       { ((unsigned*)&c1)[(i - 2) * 2] = u0; ((unsigned*)&c1)[(i - 2) * 2 + 1] = u1; }
        }
        *(s16x8*)(Qp + tile) = c0;
        *(s16x8*)(Qp + tile + 8) = c1;
    }
    {   // k
        float mu = t1 * (1.0f / 64.0f);
        float var = t2 * (1.0f / 64.0f) - mu * mu;
        float rstd = rsqrtf(var + EPS);
        s16x8 c0, c1;
        #pragma unroll
        for (int i = 0; i < 4; i++) {
            const float4 wv = *(const float4*)(kw + part * 16 + i * 4);
            const float4 bv = *(const float4*)(kb + part * 16 + i * 4);
            float a0 = (k[i].x - mu) * rstd * wv.x + bv.x;
            float a1 = (k[i].y - mu) * rstd * wv.y + bv.y;
            float a2 = (k[i].z - mu) * rstd * wv.z + bv.z;
            float a3 = (k[i].w - mu) * rstd * wv.w + bv.w;
            unsigned u0 = pk2bf(a0, a1), u1 = pk2bf(a2, a3);
            if (i < 2) { ((unsigned*)&c0)[i * 2] = u0; ((unsigned*)&c0)[i * 2 + 1] = u1; }
            else       { ((unsigned*)&c1)[(i - 2) * 2] = u0; ((unsigned*)&c1)[(i - 2) * 2 + 1] = u1; }
        }
        *(s16x8*)(Kp + tile) = c0;
        *(s16x8*)(Kp + tile + 8) = c1;
    }
    {   // v -> LDS (bf16)
        s16x8 c0, c1;
        #pragma unroll
        for (int i = 0; i < 4; i++) {
            unsigned u0 = pk2bf(v[i].x, v[i].y), u1 = pk2bf(v[i].z, v[i].w);
            if (i < 2) { ((unsigned*)&c0)[i * 2] = u0; ((unsigned*)&c0)[i * 2 + 1] = u1; }
            else       { ((unsigned*)&c1)[(i - 2) * 2] = u0; ((unsigned*)&c1)[(i - 2) * 2 + 1] = u1; }
        }
        *(s16x8*)&vlds[rl][part * 16] = c0;
        *(s16x8*)&vlds[rl][part * 16 + 8] = c1;
    }
    __syncthreads();
    // Vp: permuted transpose; each thread writes two 16B chunks
    #pragma unroll
    for (int cc = 0; cc < 2; cc++) {
        int c = tid * 2 + cc;
        int pq = c & 3, d = (c >> 2) & 63, nb = c >> 8;
        s16x8 o;
        #pragma unroll
        for (int jj = 0; jj < 4; jj++) {
            o[jj]     = (short)vlds[nb * 32 + pq * 4 + jj][d];
            o[4 + jj] = (short)vlds[nb * 32 + 16 + pq * 4 + jj][d];
        }
        size_t off = (((size_t)bh * 32 + nt * 2 + nb) * 64 + d) * 32 + pq * 8;
        *(s16x8*)(Vp + off) = o;
    }
}

// ---------------- Kernel 2: convert proj_w to bf16 (vectorized) ----------------
__global__ __launch_bounds__(256)
void cvt_kernel(const float* __restrict__ in, unsigned short* __restrict__ outp, int n4) {
    int i = blockIdx.x * 256 + threadIdx.x;
    if (i < n4) {
        float4 f = *(const float4*)(in + (size_t)i * 4);
        uint2 u; u.x = pk2bf(f.x, f.y); u.y = pk2bf(f.z, f.w);
        *(uint2*)(outp + (size_t)i * 4) = u;
    }
}

// ---------------- Kernel 3: flash attention ----------------
// si=1: 16 q-rows/wave, 64 rows/block, 1536 blocks (~6 blocks/CU -> ~20-24 waves/CU).
// Static-offset-free softmax (shift-invariance: exp2(s) <= 2^11.6, no overflow).
// K/V register double-buffered; fragment-native layouts; no LDS in main loop.
__global__ __launch_bounds__(256, 5)
void attn_kernel(const unsigned short* __restrict__ Qp,
                 const unsigned short* __restrict__ Kp,
                 const unsigned short* __restrict__ Vp,
                 unsigned short* __restrict__ Xb) {
    int bid = blockIdx.x;
    int bh = bid % BH;           // same-head blocks 96 apart -> same XCD
    int mt = bid / BH;           // 0..15
    int b = bh / NH, h = bh % NH;
    int tid = threadIdx.x;
    int w = tid >> 6, ln = tid & 63;
    int l16 = ln & 15, quad = ln >> 4;

    __shared__ __attribute__((aligned(16))) unsigned short Ol[4][16][72];

    const unsigned short* Qb = Qp + (size_t)bh * 65536;
    const unsigned short* Kb = Kp + (size_t)bh * 65536;
    const unsigned short* Vb = Vp + (size_t)bh * 65536;

    int m0 = mt * 64 + w * 16;
    int koff = l16 * 32 + quad * 8;

    s16x8 qf[2];
    #pragma unroll
    for (int ch = 0; ch < 2; ch++)
        qf[ch] = *(const s16x8*)(Qb + (size_t)((mt * 4 + w) * 2 + ch) * 512 + koff);

    f32x4 o[4];
    float lp = 0.f;
    #pragma unroll
    for (int t = 0; t < 4; t++) o[t] = (f32x4){0.f, 0.f, 0.f, 0.f};

    s16x8 kfA[2][2], vfA[4], kfB[2][2], vfB[4];

#define LOADK(dst, nn)                                                          \
    _Pragma("unroll") for (int kh = 0; kh < 2; kh++)                            \
        _Pragma("unroll") for (int ch = 0; ch < 2; ch++)                        \
            dst[kh][ch] = *(const s16x8*)(Kb + (size_t)(((((nn) >> 4) + kh) * 2 + ch)) * 512 + koff);
#define LOADV(dst, nn)                                                          \
    _Pragma("unroll") for (int t = 0; t < 4; t++)                               \
        dst[t] = *(const s16x8*)(Vb + (size_t)((((nn) >> 5) * 64 + t * 16 + l16)) * 32 + quad * 8);

#define PROCESS(kf, vf)                                                         \
    {                                                                           \
        f32x4 st0 = (f32x4){0.f, 0.f, 0.f, 0.f};                                \
        st0 = __builtin_amdgcn_mfma_f32_16x16x32_bf16(kf[0][0], qf[0], st0, 0, 0, 0); \
        st0 = __builtin_amdgcn_mfma_f32_16x16x32_bf16(kf[0][1], qf[1], st0, 0, 0, 0); \
        f32x4 st1 = (f32x4){0.f, 0.f, 0.f, 0.f};                                \
        st1 = __builtin_amdgcn_mfma_f32_16x16x32_bf16(kf[1][0], qf[0], st1, 0, 0, 0); \
        st1 = __builtin_amdgcn_mfma_f32_16x16x32_bf16(kf[1][1], qf[1], st1, 0, 0, 0); \
        float p0 = fexp2(st0[0]), p1 = fexp2(st0[1]);                           \
        float p2 = fexp2(st0[2]), p3 = fexp2(st0[3]);                           \
        float p4 = fexp2(st1[0]), p5 = fexp2(st1[1]);                           \
        float p6 = fexp2(st1[2]), p7 = fexp2(st1[3]);                           \
        lp += ((p0 + p1) + (p2 + p3)) + ((p4 + p5) + (p6 + p7));                \
        union { uint4 u; s16x8 s; } pf;                                         \
        pf.u.x = pk2bf(p0, p1); pf.u.y = pk2bf(p2, p3);                         \
        pf.u.z = pk2bf(p4, p5); pf.u.w = pk2bf(p6, p7);                         \
        _Pragma("unroll") for (int t = 0; t < 4; t++)                           \
            o[t] = __builtin_amdgcn_mfma_f32_16x16x32_bf16(vf[t], pf.s, o[t], 0, 0, 0); \
    }

    LOADK(kfA, 0); LOADV(vfA, 0);
    for (int n0 = 0; n0 < N_; n0 += 64) {
        LOADK(kfB, n0 + 32); LOADV(vfB, n0 + 32);
        PROCESS(kfA, vfA);
        int nn = (n0 + 64) & (N_ - 1);
        LOADK(kfA, nn); LOADV(vfA, nn);
        PROCESS(kfB, vfB);
    }
#undef LOADK
#undef LOADV
#undef PROCESS

    // epilogue: reduce l across quads, normalize, transpose O^T via LDS, store bf16
    float lt = lp;
    lt += __shfl_xor(lt, 16, 64);
    lt += __shfl_xor(lt, 32, 64);
    float inv = 1.0f / lt;
    #pragma unroll
    for (int t = 0; t < 4; t++) {
        uint2 u;
        u.x = pk2bf(o[t][0] * inv, o[t][1] * inv);
        u.y = pk2bf(o[t][2] * inv, o[t][3] * inv);
        *(uint2*)&Ol[w][l16][t * 16 + quad * 4] = u;
    }
    s16x8 r0 = *(const s16x8*)&Ol[w][l16][quad * 16];
    s16x8 r1 = *(const s16x8*)&Ol[w][l16][quad * 16 + 8];
    size_t row = (size_t)b * N_ + m0 + l16;
    *(s16x8*)(Xb + row * DIM + h * HD + quad * 16) = r0;
    *(s16x8*)(Xb + row * DIM + h * HD + quad * 16 + 8) = r1;
}

// ---------------- Kernel 4: projection GEMM, LDS-staged via global_load_lds ----------
__global__ __launch_bounds__(256)
void proj_kernel(const unsigned short* __restrict__ Xb,
                 const unsigned short* __restrict__ Wb,
                 const float* __restrict__ pb,
                 float* __restrict__ out) {
    int bid = blockIdx.x;
    int bm = bid % 64, bn = bid / 64;   // same-bm blocks 64 apart -> same XCD (A L2 reuse)
    int tid = threadIdx.x, w = tid >> 6, ln = tid & 63;
    int l16 = ln & 15, quad = ln >> 4;
    int wm = w & 1, wn = w >> 1;

    __shared__ __attribute__((aligned(16))) unsigned short As[128 * 64];
    __shared__ __attribute__((aligned(16))) unsigned short Bs[64 * 64];

    int lr = ln >> 3;            // row-within-DMA-instr 0..7
    int gc = (ln & 7) ^ lr;      // swizzled global chunk this lane fetches

    const unsigned short* Ag = Xb + (size_t)(bm * 128 + w * 32 + lr) * DIM + gc * 8;
    const unsigned short* Bg = Wb + (size_t)(bn * 64 + w * 16 + lr) * DIM + gc * 8;

    f32x4 c[4][2];
    #pragma unroll
    for (int t = 0; t < 4; t++)
        #pragma unroll
        for (int u = 0; u < 2; u++) c[t][u] = (f32x4){0.f, 0.f, 0.f, 0.f};

    int sw = l16 & 7;            // row-swizzle term for fragment reads

    for (int kk = 0; kk < DIM; kk += 64) {
        __syncthreads();
        #pragma unroll
        for (int j = 0; j < 4; j++)
            async_cp16(Ag + (size_t)j * 8 * DIM + kk, As + (w * 32 + j * 8) * 64);
        #pragma unroll
        for (int j = 0; j < 2; j++)
            async_cp16(Bg + (size_t)j * 8 * DIM + kk, Bs + (w * 16 + j * 8) * 64);
        __syncthreads();

        #pragma unroll
        for (int kh = 0; kh < 2; kh++) {
            s16x8 af[4], bf[2];
            #pragma unroll
            for (int t = 0; t < 4; t++) {
                int m = wm * 64 + t * 16 + l16;
                af[t] = *(const s16x8*)(As + m * 64 + (((kh * 4 + quad) ^ sw) * 8));
            }
            #pragma unroll
            for (int u = 0; u < 2; u++) {
                int n = wn * 32 + u * 16 + l16;
                bf[u] = *(const s16x8*)(Bs + n * 64 + (((kh * 4 + quad) ^ sw) * 8));
            }
            #pragma unroll
            for (int t = 0; t < 4; t++)
                #pragma unroll
                for (int u = 0; u < 2; u++)
                    c[t][u] = __builtin_amdgcn_mfma_f32_16x16x32_bf16(af[t], bf[u], c[t][u], 0, 0, 0);
        }
    }

    int m0 = bm * 128 + wm * 64;
    int n0 = bn * 64 + wn * 32;
    #pragma unroll
    for (int u = 0; u < 2; u++) {
        float bias = pb[n0 + u * 16 + l16];
        #pragma unroll
        for (int t = 0; t < 4; t++)
            #pragma unroll
            for (int r = 0; r < 4; r++) {
                int row = m0 + t * 16 + quad * 4 + r;
                out[(size_t)row * DIM + n0 + u * 16 + l16] = c[t][u][r] + bias;
            }
    }
}

extern "C" void kernel_launch(void* const* d_in, const int* in_sizes, int n_in,
                              void* d_out, int out_size, void* d_ws, size_t ws_size,
                              hipStream_t stream) {
    const float* QKV = (const float*)d_in[0];
    const float* qw  = (const float*)d_in[1];
    const float* qb  = (const float*)d_in[2];
    const float* kw  = (const float*)d_in[3];
    const float* kb  = (const float*)d_in[4];
    const float* pw  = (const float*)d_in[5];
    const float* pb  = (const float*)d_in[6];
    float* out = (float*)d_out;

    unsigned short* Qp = (unsigned short*)d_ws;                 // 96*65536
    unsigned short* Kp = Qp + (size_t)BH * 65536;
    unsigned short* Vp = Kp + (size_t)BH * 65536;
    unsigned short* Xb = Vp + (size_t)BH * 65536;               // 8192*768
    unsigned short* Wb = Xb + (size_t)B_ * N_ * DIM;            // 768*768

    ln_pack_kernel<<<BH * 16, 256, 0, stream>>>(QKV, qw, qb, kw, kb, Qp, Kp, Vp);
    cvt_kernel<<<(DIM * DIM / 4 + 255) / 256, 256, 0, stream>>>(pw, Wb, DIM * DIM / 4);
    attn_kernel<<<BH * 16, 256, 0, stream>>>(Qp, Kp, Vp, Xb);
    proj_kernel<<<64 * 12, 256, 0, stream>>>(Xb, Wb, pb, out);
}

// Round 7
// 182.525 us; speedup vs baseline: 1.2987x; 1.2987x over previous
//
#include <hip/hip_runtime.h>
#include <hip/hip_bf16.h>

#define DIM 768
#define NH 12
#define HD 64
#define B_ 8
#define N_ 1024
#define BH (B_*NH)
#define EPS 1e-5f
// fold 1/sqrt(64) * log2(e) into q at pack time -> scores arrive in exp2 domain
#define QSCALE 0.18033688011112042f

typedef short s16x8 __attribute__((ext_vector_type(8)));
typedef float f32x4 __attribute__((ext_vector_type(4)));

__device__ __forceinline__ unsigned pk2bf(float a, float b) {
    __hip_bfloat162 h = __float22bfloat162_rn(float2{a, b});
    union { __hip_bfloat162 h; unsigned u; } cv; cv.h = h;
    return cv.u;
}

__device__ __forceinline__ float fexp2(float x) {
#if __has_builtin(__builtin_amdgcn_exp2f)
    return __builtin_amdgcn_exp2f(x);
#else
    return exp2f(x);
#endif
}

__device__ __forceinline__ void async_cp16(const void* g, void* l) {
    __builtin_amdgcn_global_load_lds(
        (const __attribute__((address_space(1))) unsigned*)g,
        (__attribute__((address_space(3))) unsigned*)l, 16, 0, 0);
}

// ---------------- Kernel 1: LayerNorm q,k + pack into fragment-native layouts ---------
__global__ __launch_bounds__(256)
void ln_pack_kernel(const float* __restrict__ QKV,
                    const float* __restrict__ qw, const float* __restrict__ qb,
                    const float* __restrict__ kw, const float* __restrict__ kb,
                    unsigned short* __restrict__ Qp,
                    unsigned short* __restrict__ Kp,
                    unsigned short* __restrict__ Vp) {
    int bid = blockIdx.x;
    int bh = bid >> 4, nt = bid & 15;
    int b = bh / NH, h = bh % NH;
    int tid = threadIdx.x, w = tid >> 6, ln = tid & 63;
    int rl = w * 16 + (ln >> 2);     // local row 0..63
    int part = ln & 3;               // dims part*16 .. part*16+15
    int n = nt * 64 + rl;

    __shared__ __attribute__((aligned(16))) unsigned short vlds[64][72];

    size_t base = ((size_t)(b * N_ + n)) * (3 * DIM) + h * HD + part * 16;
    float4 q[4], k[4], v[4];
    #pragma unroll
    for (int i = 0; i < 4; i++) {
        q[i] = *(const float4*)(QKV + base + i * 4);
        k[i] = *(const float4*)(QKV + base + DIM + i * 4);
        v[i] = *(const float4*)(QKV + base + 2 * DIM + i * 4);
    }

    float s1 = 0.f, s2 = 0.f, t1 = 0.f, t2 = 0.f;
    #pragma unroll
    for (int i = 0; i < 4; i++) {
        s1 += (q[i].x + q[i].y) + (q[i].z + q[i].w);
        s2 += (q[i].x * q[i].x + q[i].y * q[i].y) + (q[i].z * q[i].z + q[i].w * q[i].w);
        t1 += (k[i].x + k[i].y) + (k[i].z + k[i].w);
        t2 += (k[i].x * k[i].x + k[i].y * k[i].y) + (k[i].z * k[i].z + k[i].w * k[i].w);
    }
    #pragma unroll
    for (int m = 1; m < 4; m <<= 1) {
        s1 += __shfl_xor(s1, m, 64);
        s2 += __shfl_xor(s2, m, 64);
        t1 += __shfl_xor(t1, m, 64);
        t2 += __shfl_xor(t2, m, 64);
    }

    int ch = part >> 1;
    size_t tile = (((size_t)bh * 64 + (n >> 4)) * 2 + ch) * 512 + (size_t)(n & 15) * 32 + (part & 1) * 16;

    {   // q
        float mu = s1 * (1.0f / 64.0f);
        float var = s2 * (1.0f / 64.0f) - mu * mu;
        float rstd = rsqrtf(var + EPS);
        s16x8 c0, c1;
        #pragma unroll
        for (int i = 0; i < 4; i++) {
            const float4 wv = *(const float4*)(qw + part * 16 + i * 4);
            const float4 bv = *(const float4*)(qb + part * 16 + i * 4);
            float a0 = ((q[i].x - mu) * rstd * wv.x + bv.x) * QSCALE;
            float a1 = ((q[i].y - mu) * rstd * wv.y + bv.y) * QSCALE;
            float a2 = ((q[i].z - mu) * rstd * wv.z + bv.z) * QSCALE;
            float a3 = ((q[i].w - mu) * rstd * wv.w + bv.w) * QSCALE;
            unsigned u0 = pk2bf(a0, a1), u1 = pk2bf(a2, a3);
            if (i < 2) { ((unsigned*)&c0)[i * 2] = u0; ((unsigned*)&c0)[i * 2 + 1] = u1; }
            else       { ((unsigned*)&c1)[(i - 2) * 2] = u0; ((unsigned*)&c1)[(i - 2) * 2 + 1] = u1; }
        }
        *(s16x8*)(Qp + tile) = c0;
        *(s16x8*)(Qp + tile + 8) = c1;
    }
    {   // k
        float mu = t1 * (1.0f / 64.0f);
        float var = t2 * (1.0f / 64.0f) - mu * mu;
        float rstd = rsqrtf(var + EPS);
        s16x8 c0, c1;
        #pragma unroll
        for (int i = 0; i < 4; i++) {
            const float4 wv = *(const float4*)(kw + part * 16 + i * 4);
            const float4 bv = *(const float4*)(kb + part * 16 + i * 4);
            float a0 = (k[i].x - mu) * rstd * wv.x + bv.x;
            float a1 = (k[i].y - mu) * rstd * wv.y + bv.y;
            float a2 = (k[i].z - mu) * rstd * wv.z + bv.z;
            float a3 = (k[i].w - mu) * rstd * wv.w + bv.w;
            unsigned u0 = pk2bf(a0, a1), u1 = pk2bf(a2, a3);
            if (i < 2) { ((unsigned*)&c0)[i * 2] = u0; ((unsigned*)&c0)[i * 2 + 1] = u1; }
            else       { ((unsigned*)&c1)[(i - 2) * 2] = u0; ((unsigned*)&c1)[(i - 2) * 2 + 1] = u1; }
        }
        *(s16x8*)(Kp + tile) = c0;
        *(s16x8*)(Kp + tile + 8) = c1;
    }
    {   // v -> LDS (bf16)
        s16x8 c0, c1;
        #pragma unroll
        for (int i = 0; i < 4; i++) {
            unsigned u0 = pk2bf(v[i].x, v[i].y), u1 = pk2bf(v[i].z, v[i].w);
            if (i < 2) { ((unsigned*)&c0)[i * 2] = u0; ((unsigned*)&c0)[i * 2 + 1] = u1; }
            else       { ((unsigned*)&c1)[(i - 2) * 2] = u0; ((unsigned*)&c1)[(i - 2) * 2 + 1] = u1; }
        }
        *(s16x8*)&vlds[rl][part * 16] = c0;
        *(s16x8*)&vlds[rl][part * 16 + 8] = c1;
    }
    __syncthreads();
    // Vp: permuted transpose; each thread writes two 16B chunks
    #pragma unroll
    for (int cc = 0; cc < 2; cc++) {
        int c = tid * 2 + cc;
        int pq = c & 3, d = (c >> 2) & 63, nb = c >> 8;
        s16x8 o;
        #pragma unroll
        for (int jj = 0; jj < 4; jj++) {
            o[jj]     = (short)vlds[nb * 32 + pq * 4 + jj][d];
            o[4 + jj] = (short)vlds[nb * 32 + 16 + pq * 4 + jj][d];
        }
        size_t off = (((size_t)bh * 32 + nt * 2 + nb) * 64 + d) * 32 + pq * 8;
        *(s16x8*)(Vp + off) = o;
    }
}

// ---------------- Kernel 2: convert proj_w to bf16 (vectorized) ----------------
__global__ __launch_bounds__(256)
void cvt_kernel(const float* __restrict__ in, unsigned short* __restrict__ outp, int n4) {
    int i = blockIdx.x * 256 + threadIdx.x;
    if (i < n4) {
        float4 f = *(const float4*)(in + (size_t)i * 4);
        uint2 u; u.x = pk2bf(f.x, f.y); u.y = pk2bf(f.z, f.w);
        *(uint2*)(outp + (size_t)i * 4) = u;
    }
}

// ---------------- Kernel 3: flash attention, LDS-staged K/V ----------------
// si=2 (32 q-rows/wave), 128 rows/block, 768 blocks (3/CU, bh%96 XCD-pinned).
// K/V staged per block into double-buffered LDS via global_load_lds (shared by all
// 4 waves -> 4x less L2 traffic than per-wave register loads, the R6 lesson).
// Softmax: exp2-domain, shift-free (|s|<=11.6, no overflow); l accumulated by a
// ones-row MFMA on the PV pass (VALU reduction tree -> MFMA pipe).
__global__ __launch_bounds__(256, 3)
void attn_kernel(const unsigned short* __restrict__ Qp,
                 const unsigned short* __restrict__ Kp,
                 const unsigned short* __restrict__ Vp,
                 unsigned short* __restrict__ Xb) {
    int bid = blockIdx.x;
    int bh = bid % BH;           // same-head blocks 96 apart -> same XCD
    int mt = bid / BH;           // 0..7
    int b = bh / NH, h = bh % NH;
    int tid = threadIdx.x;
    int w = tid >> 6, ln = tid & 63;
    int l16 = ln & 15, quad = ln >> 4;

    // 2 buffers x (K: 4 tiles x 2ch x 512 = 4096 elems | V: 2 blocks x 2048 = 4096 elems)
    __shared__ __attribute__((aligned(16))) unsigned short Sh[2][8192];
    unsigned short (*Ol)[16][72] = (unsigned short (*)[16][72])&Sh[0][0];  // epilogue alias

    const unsigned short* Qb = Qp + (size_t)bh * 65536;
    const unsigned short* Kb = Kp + (size_t)bh * 65536;
    const unsigned short* Vb = Vp + (size_t)bh * 65536;

    int m0 = mt * 128 + w * 32;
    int koff = l16 * 32 + quad * 8;

    s16x8 qf[2][2];
    #pragma unroll
    for (int si = 0; si < 2; si++)
        #pragma unroll
        for (int ch = 0; ch < 2; ch++)
            qf[si][ch] = *(const s16x8*)(Qb + (size_t)((mt * 8 + w * 2 + si) * 2 + ch) * 512 + koff);

    const s16x8 ones = {0x3F80, 0x3F80, 0x3F80, 0x3F80, 0x3F80, 0x3F80, 0x3F80, 0x3F80};

    f32x4 o[2][4], o4[2];
    #pragma unroll
    for (int si = 0; si < 2; si++) {
        #pragma unroll
        for (int t = 0; t < 4; t++) o[si][t] = (f32x4){0.f, 0.f, 0.f, 0.f};
        o4[si] = (f32x4){0.f, 0.f, 0.f, 0.f};
    }

    // stage 16KB for 64 keys at n0 into Sh[s]: waves 0,1 -> K (8KB), waves 2,3 -> V (8KB)
#define STAGE(s, n0)                                                            \
    {                                                                           \
        if (w < 2) {                                                            \
            const unsigned short* g = Kb + (size_t)((n0) >> 4) * 1024 + (size_t)w * 2048 + ln * 8; \
            _Pragma("unroll") for (int j = 0; j < 4; j++)                       \
                async_cp16(g + j * 512, &Sh[s][w * 2048 + j * 512]);            \
        } else {                                                                \
            const unsigned short* g = Vb + (size_t)((n0) >> 5) * 2048 + (size_t)(w - 2) * 2048 + ln * 8; \
            _Pragma("unroll") for (int j = 0; j < 4; j++)                       \
                async_cp16(g + j * 512, &Sh[s][4096 + (w - 2) * 2048 + j * 512]); \
        }                                                                       \
    }

    STAGE(0, 0);
    for (int n0 = 0; n0 < N_; n0 += 64) {
        int cur = (n0 >> 6) & 1;
        __syncthreads();                     // buf[cur] DMA complete; prior reads drained
        if (n0 + 64 < N_) STAGE(cur ^ 1, n0 + 64);

        const unsigned short* Ks = &Sh[cur][0];
        const unsigned short* Vs = &Sh[cur][4096];
        #pragma unroll
        for (int h2 = 0; h2 < 2; h2++) {     // two 32-key halves
            s16x8 kf[2][2];
            #pragma unroll
            for (int kh = 0; kh < 2; kh++)
                #pragma unroll
                for (int ch = 0; ch < 2; ch++)
                    kf[kh][ch] = *(const s16x8*)(Ks + ((h2 * 2 + kh) * 2 + ch) * 512 + koff);
            s16x8 vf[4];
            #pragma unroll
            for (int t = 0; t < 4; t++)
                vf[t] = *(const s16x8*)(Vs + h2 * 2048 + (t * 16 + l16) * 32 + quad * 8);

            #pragma unroll
            for (int si = 0; si < 2; si++) {
                f32x4 st0 = (f32x4){0.f, 0.f, 0.f, 0.f};
                st0 = __builtin_amdgcn_mfma_f32_16x16x32_bf16(kf[0][0], qf[si][0], st0, 0, 0, 0);
                st0 = __builtin_amdgcn_mfma_f32_16x16x32_bf16(kf[0][1], qf[si][1], st0, 0, 0, 0);
                f32x4 st1 = (f32x4){0.f, 0.f, 0.f, 0.f};
                st1 = __builtin_amdgcn_mfma_f32_16x16x32_bf16(kf[1][0], qf[si][0], st1, 0, 0, 0);
                st1 = __builtin_amdgcn_mfma_f32_16x16x32_bf16(kf[1][1], qf[si][1], st1, 0, 0, 0);

                float p0 = fexp2(st0[0]), p1 = fexp2(st0[1]);
                float p2 = fexp2(st0[2]), p3 = fexp2(st0[3]);
                float p4 = fexp2(st1[0]), p5 = fexp2(st1[1]);
                float p6 = fexp2(st1[2]), p7 = fexp2(st1[3]);
                union { uint4 u; s16x8 s; } pf;
                pf.u.x = pk2bf(p0, p1); pf.u.y = pk2bf(p2, p3);
                pf.u.z = pk2bf(p4, p5); pf.u.w = pk2bf(p6, p7);

                #pragma unroll
                for (int t = 0; t < 4; t++)
                    o[si][t] = __builtin_amdgcn_mfma_f32_16x16x32_bf16(vf[t], pf.s, o[si][t], 0, 0, 0);
                o4[si] = __builtin_amdgcn_mfma_f32_16x16x32_bf16(ones, pf.s, o4[si], 0, 0, 0);
            }
        }
    }
#undef STAGE

    __syncthreads();  // staging reads done before Ol (aliased) is written
    #pragma unroll
    for (int si = 0; si < 2; si++) {
        float inv = 1.0f / o4[si][0];        // l for qrow l16 (all 4 elems equal)
        #pragma unroll
        for (int t = 0; t < 4; t++) {
            uint2 u;
            u.x = pk2bf(o[si][t][0] * inv, o[si][t][1] * inv);
            u.y = pk2bf(o[si][t][2] * inv, o[si][t][3] * inv);
            *(uint2*)&Ol[w][l16][t * 16 + quad * 4] = u;
        }
        s16x8 r0 = *(const s16x8*)&Ol[w][l16][quad * 16];
        s16x8 r1 = *(const s16x8*)&Ol[w][l16][quad * 16 + 8];
        size_t row = (size_t)b * N_ + m0 + si * 16 + l16;
        *(s16x8*)(Xb + row * DIM + h * HD + quad * 16) = r0;
        *(s16x8*)(Xb + row * DIM + h * HD + quad * 16 + 8) = r1;
    }
}

// ---------------- Kernel 4: projection GEMM, LDS-staged via global_load_lds ----------
__global__ __launch_bounds__(256)
void proj_kernel(const unsigned short* __restrict__ Xb,
                 const unsigned short* __restrict__ Wb,
                 const float* __restrict__ pb,
                 float* __restrict__ out) {
    int bid = blockIdx.x;
    int bm = bid % 64, bn = bid / 64;   // same-bm blocks 64 apart -> same XCD (A L2 reuse)
    int tid = threadIdx.x, w = tid >> 6, ln = tid & 63;
    int l16 = ln & 15, quad = ln >> 4;
    int wm = w & 1, wn = w >> 1;

    __shared__ __attribute__((aligned(16))) unsigned short As[128 * 64];
    __shared__ __attribute__((aligned(16))) unsigned short Bs[64 * 64];

    int lr = ln >> 3;            // row-within-DMA-instr 0..7
    int gc = (ln & 7) ^ lr;      // swizzled global chunk this lane fetches

    const unsigned short* Ag = Xb + (size_t)(bm * 128 + w * 32 + lr) * DIM + gc * 8;
    const unsigned short* Bg = Wb + (size_t)(bn * 64 + w * 16 + lr) * DIM + gc * 8;

    f32x4 c[4][2];
    #pragma unroll
    for (int t = 0; t < 4; t++)
        #pragma unroll
        for (int u = 0; u < 2; u++) c[t][u] = (f32x4){0.f, 0.f, 0.f, 0.f};

    int sw = l16 & 7;            // row-swizzle term for fragment reads

    for (int kk = 0; kk < DIM; kk += 64) {
        __syncthreads();
        #pragma unroll
        for (int j = 0; j < 4; j++)
            async_cp16(Ag + (size_t)j * 8 * DIM + kk, As + (w * 32 + j * 8) * 64);
        #pragma unroll
        for (int j = 0; j < 2; j++)
            async_cp16(Bg + (size_t)j * 8 * DIM + kk, Bs + (w * 16 + j * 8) * 64);
        __syncthreads();

        #pragma unroll
        for (int kh = 0; kh < 2; kh++) {
            s16x8 af[4], bf[2];
            #pragma unroll
            for (int t = 0; t < 4; t++) {
                int m = wm * 64 + t * 16 + l16;
                af[t] = *(const s16x8*)(As + m * 64 + (((kh * 4 + quad) ^ sw) * 8));
            }
            #pragma unroll
            for (int u = 0; u < 2; u++) {
                int n = wn * 32 + u * 16 + l16;
                bf[u] = *(const s16x8*)(Bs + n * 64 + (((kh * 4 + quad) ^ sw) * 8));
            }
            #pragma unroll
            for (int t = 0; t < 4; t++)
                #pragma unroll
                for (int u = 0; u < 2; u++)
                    c[t][u] = __builtin_amdgcn_mfma_f32_16x16x32_bf16(af[t], bf[u], c[t][u], 0, 0, 0);
        }
    }

    int m0 = bm * 128 + wm * 64;
    int n0 = bn * 64 + wn * 32;
    #pragma unroll
    for (int u = 0; u < 2; u++) {
        float bias = pb[n0 + u * 16 + l16];
        #pragma unroll
        for (int t = 0; t < 4; t++)
            #pragma unroll
            for (int r = 0; r < 4; r++) {
                int row = m0 + t * 16 + quad * 4 + r;
                out[(size_t)row * DIM + n0 + u * 16 + l16] = c[t][u][r] + bias;
            }
    }
}

extern "C" void kernel_launch(void* const* d_in, const int* in_sizes, int n_in,
                              void* d_out, int out_size, void* d_ws, size_t ws_size,
                              hipStream_t stream) {
    const float* QKV = (const float*)d_in[0];
    const float* qw  = (const float*)d_in[1];
    const float* qb  = (const float*)d_in[2];
    const float* kw  = (const float*)d_in[3];
    const float* kb  = (const float*)d_in[4];
    const float* pw  = (const float*)d_in[5];
    const float* pb  = (const float*)d_in[6];
    float* out = (float*)d_out;

    unsigned short* Qp = (unsigned short*)d_ws;                 // 96*65536
    unsigned short* Kp = Qp + (size_t)BH * 65536;
    unsigned short* Vp = Kp + (size_t)BH * 65536;
    unsigned short* Xb = Vp + (size_t)BH * 65536;               // 8192*768
    unsigned short* Wb = Xb + (size_t)B_ * N_ * DIM;            // 768*768

    ln_pack_kernel<<<BH * 16, 256, 0, stream>>>(QKV, qw, qb, kw, kb, Qp, Kp, Vp);
    cvt_kernel<<<(DIM * DIM / 4 + 255) / 256, 256, 0, stream>>>(pw, Wb, DIM * DIM / 4);
    attn_kernel<<<BH * 8, 256, 0, stream>>>(Qp, Kp, Vp, Xb);
    proj_kernel<<<64 * 12, 256, 0, stream>>>(Xb, Wb, pb, out);
}